// Round 1
// baseline (1754.958 us; speedup 1.0000x reference)
//
#include <hip/hip_runtime.h>
#include <stdint.h>

#define N_TOTAL  1327104     // 384*384*9
#define KPRE     12000
#define KPOST    2000
#define NPAD     12032       // KPRE padded to 64
#define WORDS    188         // 12032/64
#define CAND_CAP 16384
#define IMGLIM   6144.0f

// 9 base anchors (ratio-major, scale-minor). All centered at (7.5,7.5) so
// cx = col*16 + 8, cy = row*16 + 8 exactly; only (w,h) vary per anchor.
__constant__ float c_aw[9] = {184.f,368.f,736.f,128.f,256.f,512.f, 88.f,176.f,352.f};
__constant__ float c_ah[9] = { 96.f,192.f,384.f,128.f,256.f,512.f,176.f,352.f,704.f};

// block FMA contraction: numpy computes d*w (round) then +c (round)
__device__ __forceinline__ float mul_sep(float a, float b) {
    float r = a * b;
    asm volatile("" : "+v"(r));
    return r;
}

__device__ __forceinline__ void compute_box(int idx, const float4 d,
        float& ox0, float& oy0, float& ox1, float& oy1, bool& keep)
{
    int a    = idx % 9;
    int cell = idx / 9;
    int col  = cell % 384;
    int row  = cell / 384;
    float w = c_aw[a], h = c_ah[a];
    float cx = (float)(col * 16 + 8);
    float cy = (float)(row * 16 + 8);
    float pcx = mul_sep(d.x, w) + cx;
    float pcy = mul_sep(d.y, h) + cy;
    float pw = expf(d.z) * w;
    float ph = expf(d.w) * h;
    // 0.5f*pw is exact halving -> contraction-safe
    float x0 = pcx - 0.5f * pw;
    float y0 = pcy - 0.5f * ph;
    float x1 = pcx + 0.5f * pw;
    float y1 = pcy + 0.5f * ph;
    ox0 = fminf(fmaxf(x0, 0.f), IMGLIM);
    oy0 = fminf(fmaxf(y0, 0.f), IMGLIM);
    ox1 = fminf(fmaxf(x1, 0.f), IMGLIM);
    oy1 = fminf(fmaxf(y1, 0.f), IMGLIM);
    keep = ((ox1 - ox0) >= 16.f) && ((oy1 - oy0) >= 16.f);
}

__global__ void k_init(uint32_t* hist1, uint32_t* hist2, uint32_t* hist3,
                       uint32_t* state, uint32_t* sorted_anchor)
{
    int t = blockIdx.x * blockDim.x + threadIdx.x;
    if      (t < 2048) hist1[t] = 0;
    else if (t < 4096) hist2[t - 2048] = 0;
    else if (t < 5120) hist3[t - 4096] = 0;
    else if (t < 5136) state[t - 5120] = 0;
    int u = t - 5136;
    if (u >= 0 && u < NPAD) sorted_anchor[u] = 0xFFFFFFFFu;
}

// keys: score bits if box passes min-size filter else 0; + pass-1 histogram (top 11 bits)
__global__ void k_keys(const float* __restrict__ delta, const float* __restrict__ score,
                       uint32_t* __restrict__ keys, uint32_t* __restrict__ hist1)
{
    __shared__ uint32_t lh[2048];
    for (int t = threadIdx.x; t < 2048; t += blockDim.x) lh[t] = 0;
    __syncthreads();
    int idx = blockIdx.x * blockDim.x + threadIdx.x;
    if (idx < N_TOTAL) {
        float4 d = ((const float4*)delta)[idx];
        float x0, y0, x1, y1; bool keep;
        compute_box(idx, d, x0, y0, x1, y1, keep);
        float s = ((const float2*)score)[idx].y;
        uint32_t key = keep ? __float_as_uint(s) : 0u;   // s in [0,1): bits monotonic
        keys[idx] = key;
        atomicAdd(&lh[key >> 21], 1u);
    }
    __syncthreads();
    for (int t = threadIdx.x; t < 2048; t += blockDim.x) {
        uint32_t c = lh[t];
        if (c) atomicAdd(&hist1[t], c);
    }
}

__global__ void k_hist2(const uint32_t* __restrict__ keys, const uint32_t* __restrict__ state,
                        uint32_t* __restrict__ hist)
{
    __shared__ uint32_t lh[2048];
    for (int t = threadIdx.x; t < 2048; t += blockDim.x) lh[t] = 0;
    __syncthreads();
    uint32_t B1 = state[0];
    int idx = blockIdx.x * blockDim.x + threadIdx.x;
    if (idx < N_TOTAL) {
        uint32_t k = keys[idx];
        if ((k >> 21) == B1) atomicAdd(&lh[(k >> 10) & 0x7FFu], 1u);
    }
    __syncthreads();
    for (int t = threadIdx.x; t < 2048; t += blockDim.x) {
        uint32_t c = lh[t];
        if (c) atomicAdd(&hist[t], c);
    }
}

__global__ void k_hist3(const uint32_t* __restrict__ keys, const uint32_t* __restrict__ state,
                        uint32_t* __restrict__ hist)
{
    __shared__ uint32_t lh[1024];
    for (int t = threadIdx.x; t < 1024; t += blockDim.x) lh[t] = 0;
    __syncthreads();
    uint32_t pfx = state[2];
    int idx = blockIdx.x * blockDim.x + threadIdx.x;
    if (idx < N_TOTAL) {
        uint32_t k = keys[idx];
        if ((k >> 10) == pfx) atomicAdd(&lh[k & 0x3FFu], 1u);
    }
    __syncthreads();
    for (int t = threadIdx.x; t < 1024; t += blockDim.x) {
        uint32_t c = lh[t];
        if (c) atomicAdd(&hist[t], c);
    }
}

// find bin containing the K-th largest, scanning bins from the top
__global__ void k_scan(const uint32_t* __restrict__ hist, uint32_t* __restrict__ state,
                       int nbins, int pass)
{
    __shared__ uint32_t lh[2048];
    for (int t = threadIdx.x; t < nbins; t += blockDim.x) lh[t] = hist[t];
    __syncthreads();
    if (threadIdx.x == 0) {
        uint32_t K = (pass == 0) ? (uint32_t)KPRE : ((pass == 1) ? state[1] : state[3]);
        if (K == 0u) K = 1u;
        uint32_t cum = 0, B = 0, rem = K;
        bool found = false;
        for (int b = nbins - 1; b >= 0; --b) {
            uint32_t h = lh[b];
            if (!found && cum + h >= K) { B = (uint32_t)b; rem = K - cum; found = true; }
            if (!found) cum += h;
        }
        if      (pass == 0) { state[0] = B; state[1] = rem; }
        else if (pass == 1) { state[2] = (state[0] << 11) | B; state[3] = rem; }
        else                { state[4] = (state[2] << 10) | B; }
    }
}

// compact all keys >= threshold into 64-bit combined keys (score desc, idx asc order)
__global__ void k_compact(const uint32_t* __restrict__ keys, uint32_t* __restrict__ state,
                          uint64_t* __restrict__ cand)
{
    uint32_t T = state[4];
    int idx = blockIdx.x * blockDim.x + threadIdx.x;
    if (idx >= N_TOTAL) return;
    uint32_t k = keys[idx];
    if (k >= T) {
        uint32_t p = atomicAdd(&state[5], 1u);
        if (p < CAND_CAP)
            cand[p] = ((uint64_t)k << 32) | (uint64_t)(0xFFFFFFFFu - (uint32_t)idx);
    }
}

// exact rank sort: rank = #{j : key_j > key_i}; keys unique -> bijective
__global__ void k_ranksort(const uint64_t* __restrict__ cand, const uint32_t* __restrict__ state,
                           uint32_t* __restrict__ sorted_anchor)
{
    __shared__ uint64_t lk[2048];
    uint32_t M = min(state[5], (uint32_t)CAND_CAP);
    int i = blockIdx.x * blockDim.x + threadIdx.x;
    uint64_t mykey = (i < (int)M) ? cand[i] : 0ull;
    uint32_t rank = 0;
    for (uint32_t base = 0; base < M; base += 2048) {
        uint32_t chunk = min(2048u, M - base);
        __syncthreads();
        for (uint32_t t = threadIdx.x; t < chunk; t += blockDim.x) lk[t] = cand[base + t];
        __syncthreads();
        if (i < (int)M)
            for (uint32_t j = 0; j < chunk; ++j) rank += (lk[j] > mykey) ? 1u : 0u;
    }
    if (i < (int)M && rank < KPRE)
        sorted_anchor[rank] = 0xFFFFFFFFu - (uint32_t)(mykey & 0xFFFFFFFFull);
}

__global__ void k_boxes(const float* __restrict__ delta, const uint32_t* __restrict__ sorted_anchor,
                        float* __restrict__ bx0, float* __restrict__ by0,
                        float* __restrict__ bx1, float* __restrict__ by1,
                        float* __restrict__ bar)
{
    int r = blockIdx.x * blockDim.x + threadIdx.x;
    if (r >= NPAD) return;
    float x0 = 0.f, y0 = 0.f, x1 = 0.f, y1 = 0.f;
    if (r < KPRE) {
        uint32_t aidx = sorted_anchor[r];
        if (aidx < (uint32_t)N_TOTAL) {
            float4 d = ((const float4*)delta)[aidx];
            bool keep;
            compute_box((int)aidx, d, x0, y0, x1, y1, keep);
        }
    }
    bx0[r] = x0; by0[r] = y0; bx1[r] = x1; by1[r] = y1;
    bar[r] = (x1 - x0) * (y1 - y0);
}

// full IoU bitmask: 188 blocks x 64 rows, LDS-staged column tiles of 256
__global__ void k_mask(const float* __restrict__ bx0, const float* __restrict__ by0,
                       const float* __restrict__ bx1, const float* __restrict__ by1,
                       const float* __restrict__ bar, uint64_t* __restrict__ mask)
{
    __shared__ float s0[256], s1[256], s2[256], s3[256], sa[256];
    int rr = threadIdx.x >> 2;
    int q  = threadIdx.x & 3;
    int r  = blockIdx.x * 64 + rr;
    float rx0 = bx0[r], ry0 = by0[r], rx1 = bx1[r], ry1 = by1[r], ra = bar[r];
    for (int c = 0; c < NPAD / 256; ++c) {
        int cb = c * 256;
        __syncthreads();
        int t = threadIdx.x;
        s0[t] = bx0[cb + t]; s1[t] = by0[cb + t];
        s2[t] = bx1[cb + t]; s3[t] = by1[cb + t];
        sa[t] = bar[cb + t];
        __syncthreads();
        uint64_t bits = 0;
        int j0 = q * 64;
        #pragma unroll 4
        for (int j = 0; j < 64; ++j) {
            int jj = j0 + j;
            float ix0 = fmaxf(rx0, s0[jj]);
            float iy0 = fmaxf(ry0, s1[jj]);
            float ix1 = fminf(rx1, s2[jj]);
            float iy1 = fminf(ry1, s3[jj]);
            float iw = fmaxf(ix1 - ix0, 0.f);
            float ih = fmaxf(iy1 - iy0, 0.f);
            float inter = iw * ih;
            float denom = ra + sa[jj] - inter + 1e-9f;   // ((ra+sa)-inter)+eps, as ref
            float iou = inter / denom;
            bits |= ((uint64_t)(iou > 0.7f)) << j;
        }
        mask[(size_t)r * WORDS + (size_t)(c * 4 + q)] = bits;
    }
}

// serial greedy NMS: single wave; suppression mask in registers (3 u64/lane)
__global__ void k_nms(const uint64_t* __restrict__ mask, int* __restrict__ sel,
                      uint32_t* __restrict__ state)
{
    int lane = threadIdx.x;           // blockDim = 64 (one wave)
    uint64_t p0 = 0, p1 = 0, p2 = 0;  // lane owns words lane, 64+lane, 128+lane
    int cnt = 0, iw = 0;
    while (iw < WORDS && cnt < KPOST) {
        int slot = iw >> 6;
        uint64_t v = (slot == 0) ? p0 : ((slot == 1) ? p1 : p2);
        uint64_t cur = (uint64_t)__shfl((unsigned long long)v, iw & 63, 64);
        uint64_t validm = (iw == WORDS - 1) ? 0xFFFFFFFFull : ~0ull;  // cols < 12000
        uint64_t avail = (~cur) & validm;
        if (avail == 0ull) { ++iw; continue; }
        int b = __ffsll((unsigned long long)avail) - 1;
        int i = iw * 64 + b;
        if (lane == 0) sel[cnt] = i;
        ++cnt;
        const uint64_t* row = mask + (size_t)i * WORDS;
        p0 |= row[lane];
        p1 |= row[64 + lane];
        if (lane < WORDS - 128) p2 |= row[128 + lane];
        // row's own bit i is set (self-IoU=1>0.7), so avail shrinks -> no livelock
    }
    if (lane == 0) state[6] = (uint32_t)cnt;
}

__global__ void k_gather(const float* __restrict__ bx0, const float* __restrict__ by0,
                         const float* __restrict__ bx1, const float* __restrict__ by1,
                         const int* __restrict__ sel, const uint32_t* __restrict__ state,
                         float4* __restrict__ out)
{
    int slot = blockIdx.x * blockDim.x + threadIdx.x;
    if (slot >= KPOST) return;
    uint32_t cnt = state[6];
    float4 v = make_float4(0.f, 0.f, 0.f, 0.f);
    if ((uint32_t)slot < cnt) {
        int i = sel[slot];
        v = make_float4(bx0[i], by0[i], bx1[i], by1[i]);
    }
    out[slot] = v;
}

extern "C" void kernel_launch(void* const* d_in, const int* in_sizes, int n_in,
                              void* d_out, int out_size, void* d_ws, size_t ws_size,
                              hipStream_t stream)
{
    const float* delta = (const float*)d_in[0];
    const float* score = (const float*)d_in[1];
    float4* out = (float4*)d_out;

    uint8_t* p = (uint8_t*)d_ws;
    auto alloc = [&](size_t bytes) -> void* {
        void* r = (void*)p;
        p += (bytes + 255) & ~(size_t)255;
        return r;
    };
    uint32_t* keys          = (uint32_t*)alloc((size_t)N_TOTAL * 4);
    uint32_t* hist1         = (uint32_t*)alloc(2048 * 4);
    uint32_t* hist2         = (uint32_t*)alloc(2048 * 4);
    uint32_t* hist3         = (uint32_t*)alloc(1024 * 4);
    uint32_t* state         = (uint32_t*)alloc(64);
    uint64_t* cand          = (uint64_t*)alloc((size_t)CAND_CAP * 8);
    uint32_t* sorted_anchor = (uint32_t*)alloc((size_t)NPAD * 4);
    float*    bx0           = (float*)alloc((size_t)NPAD * 4);
    float*    by0           = (float*)alloc((size_t)NPAD * 4);
    float*    bx1           = (float*)alloc((size_t)NPAD * 4);
    float*    by1           = (float*)alloc((size_t)NPAD * 4);
    float*    bar           = (float*)alloc((size_t)NPAD * 4);
    int*      sel           = (int*)alloc((size_t)KPOST * 4);
    uint64_t* mask          = (uint64_t*)alloc((size_t)NPAD * WORDS * 8);
    (void)ws_size; (void)n_in; (void)in_sizes; (void)out_size;

    const int B = 256;
    const int gN = (N_TOTAL + B - 1) / B;

    hipLaunchKernelGGL(k_init, dim3(68), dim3(B), 0, stream,
                       hist1, hist2, hist3, state, sorted_anchor);
    hipLaunchKernelGGL(k_keys, dim3(gN), dim3(B), 0, stream, delta, score, keys, hist1);
    hipLaunchKernelGGL(k_scan, dim3(1), dim3(B), 0, stream, hist1, state, 2048, 0);
    hipLaunchKernelGGL(k_hist2, dim3(gN), dim3(B), 0, stream, keys, state, hist2);
    hipLaunchKernelGGL(k_scan, dim3(1), dim3(B), 0, stream, hist2, state, 2048, 1);
    hipLaunchKernelGGL(k_hist3, dim3(gN), dim3(B), 0, stream, keys, state, hist3);
    hipLaunchKernelGGL(k_scan, dim3(1), dim3(B), 0, stream, hist3, state, 1024, 2);
    hipLaunchKernelGGL(k_compact, dim3(gN), dim3(B), 0, stream, keys, state, cand);
    hipLaunchKernelGGL(k_ranksort, dim3(CAND_CAP / B), dim3(B), 0, stream,
                       cand, state, sorted_anchor);
    hipLaunchKernelGGL(k_boxes, dim3(NPAD / B), dim3(B), 0, stream,
                       delta, sorted_anchor, bx0, by0, bx1, by1, bar);
    hipLaunchKernelGGL(k_mask, dim3(NPAD / 64), dim3(B), 0, stream,
                       bx0, by0, bx1, by1, bar, mask);
    hipLaunchKernelGGL(k_nms, dim3(1), dim3(64), 0, stream, mask, sel, state);
    hipLaunchKernelGGL(k_gather, dim3((KPOST + B - 1) / B), dim3(B), 0, stream,
                       bx0, by0, bx1, by1, sel, state, out);
}

// Round 2
// 1369.833 us; speedup vs baseline: 1.2811x; 1.2811x over previous
//
#include <hip/hip_runtime.h>
#include <stdint.h>

#define N_TOTAL  1327104     // 384*384*9
#define KPRE     12000
#define KPOST    2000
#define NPAD     12032       // KPRE padded to 64
#define WORDS    188         // 12032/64
#define CAND_CAP 16384
#define IMGLIM   6144.0f

// 9 base anchors (ratio-major, scale-minor). All centered at (7.5,7.5) so
// cx = col*16 + 8, cy = row*16 + 8 exactly; only (w,h) vary per anchor.
__constant__ float c_aw[9] = {184.f,368.f,736.f,128.f,256.f,512.f, 88.f,176.f,352.f};
__constant__ float c_ah[9] = { 96.f,192.f,384.f,128.f,256.f,512.f,176.f,352.f,704.f};

// block FMA contraction: numpy computes d*w (round) then +c (round)
__device__ __forceinline__ float mul_sep(float a, float b) {
    float r = a * b;
    asm volatile("" : "+v"(r));
    return r;
}

__device__ __forceinline__ void compute_box(int idx, const float4 d,
        float& ox0, float& oy0, float& ox1, float& oy1, bool& keep)
{
    int a    = idx % 9;
    int cell = idx / 9;
    int col  = cell % 384;
    int row  = cell / 384;
    float w = c_aw[a], h = c_ah[a];
    float cx = (float)(col * 16 + 8);
    float cy = (float)(row * 16 + 8);
    float pcx = mul_sep(d.x, w) + cx;
    float pcy = mul_sep(d.y, h) + cy;
    float pw = expf(d.z) * w;
    float ph = expf(d.w) * h;
    // 0.5f*pw is exact halving -> contraction-safe
    float x0 = pcx - 0.5f * pw;
    float y0 = pcy - 0.5f * ph;
    float x1 = pcx + 0.5f * pw;
    float y1 = pcy + 0.5f * ph;
    ox0 = fminf(fmaxf(x0, 0.f), IMGLIM);
    oy0 = fminf(fmaxf(y0, 0.f), IMGLIM);
    ox1 = fminf(fmaxf(x1, 0.f), IMGLIM);
    oy1 = fminf(fmaxf(y1, 0.f), IMGLIM);
    keep = ((ox1 - ox0) >= 16.f) && ((oy1 - oy0) >= 16.f);
}

__global__ void k_init(uint32_t* hist1, uint32_t* hist2, uint32_t* hist3,
                       uint32_t* state, uint32_t* sorted_anchor)
{
    int t = blockIdx.x * blockDim.x + threadIdx.x;
    if      (t < 2048) hist1[t] = 0;
    else if (t < 4096) hist2[t - 2048] = 0;
    else if (t < 5120) hist3[t - 4096] = 0;
    else if (t < 5136) state[t - 5120] = 0;
    int u = t - 5136;
    if (u >= 0 && u < NPAD) sorted_anchor[u] = 0xFFFFFFFFu;
}

// keys: score bits if box passes min-size filter else 0; + pass-1 histogram (top 11 bits)
__global__ void k_keys(const float* __restrict__ delta, const float* __restrict__ score,
                       uint32_t* __restrict__ keys, uint32_t* __restrict__ hist1)
{
    __shared__ uint32_t lh[2048];
    for (int t = threadIdx.x; t < 2048; t += blockDim.x) lh[t] = 0;
    __syncthreads();
    int idx = blockIdx.x * blockDim.x + threadIdx.x;
    if (idx < N_TOTAL) {
        float4 d = ((const float4*)delta)[idx];
        float x0, y0, x1, y1; bool keep;
        compute_box(idx, d, x0, y0, x1, y1, keep);
        float s = ((const float2*)score)[idx].y;
        uint32_t key = keep ? __float_as_uint(s) : 0u;   // s in [0,1): bits monotonic
        keys[idx] = key;
        atomicAdd(&lh[key >> 21], 1u);
    }
    __syncthreads();
    for (int t = threadIdx.x; t < 2048; t += blockDim.x) {
        uint32_t c = lh[t];
        if (c) atomicAdd(&hist1[t], c);
    }
}

__global__ void k_hist2(const uint32_t* __restrict__ keys, const uint32_t* __restrict__ state,
                        uint32_t* __restrict__ hist)
{
    __shared__ uint32_t lh[2048];
    for (int t = threadIdx.x; t < 2048; t += blockDim.x) lh[t] = 0;
    __syncthreads();
    uint32_t B1 = state[0];
    int idx = blockIdx.x * blockDim.x + threadIdx.x;
    if (idx < N_TOTAL) {
        uint32_t k = keys[idx];
        if ((k >> 21) == B1) atomicAdd(&lh[(k >> 10) & 0x7FFu], 1u);
    }
    __syncthreads();
    for (int t = threadIdx.x; t < 2048; t += blockDim.x) {
        uint32_t c = lh[t];
        if (c) atomicAdd(&hist[t], c);
    }
}

__global__ void k_hist3(const uint32_t* __restrict__ keys, const uint32_t* __restrict__ state,
                        uint32_t* __restrict__ hist)
{
    __shared__ uint32_t lh[1024];
    for (int t = threadIdx.x; t < 1024; t += blockDim.x) lh[t] = 0;
    __syncthreads();
    uint32_t pfx = state[2];
    int idx = blockIdx.x * blockDim.x + threadIdx.x;
    if (idx < N_TOTAL) {
        uint32_t k = keys[idx];
        if ((k >> 10) == pfx) atomicAdd(&lh[k & 0x3FFu], 1u);
    }
    __syncthreads();
    for (int t = threadIdx.x; t < 1024; t += blockDim.x) {
        uint32_t c = lh[t];
        if (c) atomicAdd(&hist[t], c);
    }
}

// find bin containing the K-th largest, scanning bins from the top
__global__ void k_scan(const uint32_t* __restrict__ hist, uint32_t* __restrict__ state,
                       int nbins, int pass)
{
    __shared__ uint32_t lh[2048];
    for (int t = threadIdx.x; t < nbins; t += blockDim.x) lh[t] = hist[t];
    __syncthreads();
    if (threadIdx.x == 0) {
        uint32_t K = (pass == 0) ? (uint32_t)KPRE : ((pass == 1) ? state[1] : state[3]);
        if (K == 0u) K = 1u;
        uint32_t cum = 0, B = 0, rem = K;
        bool found = false;
        for (int b = nbins - 1; b >= 0; --b) {
            uint32_t h = lh[b];
            if (!found && cum + h >= K) { B = (uint32_t)b; rem = K - cum; found = true; }
            if (!found) cum += h;
        }
        if      (pass == 0) { state[0] = B; state[1] = rem; }
        else if (pass == 1) { state[2] = (state[0] << 11) | B; state[3] = rem; }
        else                { state[4] = (state[2] << 10) | B; }
    }
}

// compact all keys >= threshold into 64-bit combined keys (score desc, idx asc order)
__global__ void k_compact(const uint32_t* __restrict__ keys, uint32_t* __restrict__ state,
                          uint64_t* __restrict__ cand)
{
    uint32_t T = state[4];
    int idx = blockIdx.x * blockDim.x + threadIdx.x;
    if (idx >= N_TOTAL) return;
    uint32_t k = keys[idx];
    if (k >= T) {
        uint32_t p = atomicAdd(&state[5], 1u);
        if (p < CAND_CAP)
            cand[p] = ((uint64_t)k << 32) | (uint64_t)(0xFFFFFFFFu - (uint32_t)idx);
    }
}

// exact rank sort: rank = #{j : key_j > key_i}; keys unique -> bijective
__global__ void k_ranksort(const uint64_t* __restrict__ cand, const uint32_t* __restrict__ state,
                           uint32_t* __restrict__ sorted_anchor)
{
    __shared__ uint64_t lk[2048];
    uint32_t M = min(state[5], (uint32_t)CAND_CAP);
    int i = blockIdx.x * blockDim.x + threadIdx.x;
    uint64_t mykey = (i < (int)M) ? cand[i] : 0ull;
    uint32_t rank = 0;
    for (uint32_t base = 0; base < M; base += 2048) {
        uint32_t chunk = min(2048u, M - base);
        __syncthreads();
        for (uint32_t t = threadIdx.x; t < chunk; t += blockDim.x) lk[t] = cand[base + t];
        __syncthreads();
        if (i < (int)M)
            for (uint32_t j = 0; j < chunk; ++j) rank += (lk[j] > mykey) ? 1u : 0u;
    }
    if (i < (int)M && rank < KPRE)
        sorted_anchor[rank] = 0xFFFFFFFFu - (uint32_t)(mykey & 0xFFFFFFFFull);
}

__global__ void k_boxes(const float* __restrict__ delta, const uint32_t* __restrict__ sorted_anchor,
                        float* __restrict__ bx0, float* __restrict__ by0,
                        float* __restrict__ bx1, float* __restrict__ by1,
                        float* __restrict__ bar)
{
    int r = blockIdx.x * blockDim.x + threadIdx.x;
    if (r >= NPAD) return;
    float x0 = 0.f, y0 = 0.f, x1 = 0.f, y1 = 0.f;
    if (r < KPRE) {
        uint32_t aidx = sorted_anchor[r];
        if (aidx < (uint32_t)N_TOTAL) {
            float4 d = ((const float4*)delta)[aidx];
            bool keep;
            compute_box((int)aidx, d, x0, y0, x1, y1, keep);
        }
    }
    bx0[r] = x0; by0[r] = y0; bx1[r] = x1; by1[r] = y1;
    bar[r] = (x1 - x0) * (y1 - y0);
}

// full IoU bitmask: 188 blocks x 64 rows, LDS-staged column tiles of 256
__global__ void k_mask(const float* __restrict__ bx0, const float* __restrict__ by0,
                       const float* __restrict__ bx1, const float* __restrict__ by1,
                       const float* __restrict__ bar, uint64_t* __restrict__ mask)
{
    __shared__ float s0[256], s1[256], s2[256], s3[256], sa[256];
    int rr = threadIdx.x >> 2;
    int q  = threadIdx.x & 3;
    int r  = blockIdx.x * 64 + rr;
    float rx0 = bx0[r], ry0 = by0[r], rx1 = bx1[r], ry1 = by1[r], ra = bar[r];
    for (int c = 0; c < NPAD / 256; ++c) {
        int cb = c * 256;
        __syncthreads();
        int t = threadIdx.x;
        s0[t] = bx0[cb + t]; s1[t] = by0[cb + t];
        s2[t] = bx1[cb + t]; s3[t] = by1[cb + t];
        sa[t] = bar[cb + t];
        __syncthreads();
        uint64_t bits = 0;
        int j0 = q * 64;
        #pragma unroll 4
        for (int j = 0; j < 64; ++j) {
            int jj = j0 + j;
            float ix0 = fmaxf(rx0, s0[jj]);
            float iy0 = fmaxf(ry0, s1[jj]);
            float ix1 = fminf(rx1, s2[jj]);
            float iy1 = fminf(ry1, s3[jj]);
            float iw = fmaxf(ix1 - ix0, 0.f);
            float ih = fmaxf(iy1 - iy0, 0.f);
            float inter = iw * ih;
            float denom = ra + sa[jj] - inter + 1e-9f;   // ((ra+sa)-inter)+eps, as ref
            float iou = inter / denom;
            bits |= ((uint64_t)(iou > 0.7f)) << j;
        }
        mask[(size_t)r * WORDS + (size_t)(c * 4 + q)] = bits;
    }
}

// serial greedy NMS, restructured: per-WORD latency chain (188 steps) instead
// of per-selection (~2200 steps). Within a word: suppression needs only the
// 64x64 diagonal block (preloaded, 1 load/lane); full-row ORs are batched
// 16-wide after the word completes. Next word's diagonal prefetched early.
__global__ void k_nms(const uint64_t* __restrict__ mask, int* __restrict__ sel,
                      uint32_t* __restrict__ state)
{
    const int lane = threadIdx.x;     // blockDim = 64 (one wave)
    uint64_t p0 = 0, p1 = 0, p2 = 0;  // lane owns words lane, 64+lane, 128+lane
    int cnt = 0;
    uint64_t Dcur = mask[(size_t)lane * WORDS];   // diag block, word 0
    for (int iw = 0; iw < WORDS && cnt < KPOST; ++iw) {
        // prefetch next diagonal block (address independent of this word's work)
        uint64_t Dnext = 0;
        if (iw + 1 < WORDS)
            Dnext = mask[(size_t)((iw + 1) * 64 + lane) * WORDS + (size_t)(iw + 1)];
        int slot = iw >> 6;
        uint64_t pv = (slot == 0) ? p0 : ((slot == 1) ? p1 : p2);
        uint64_t cur = (uint64_t)__shfl((unsigned long long)pv, iw & 63, 64);
        uint64_t validm = (iw == WORDS - 1) ? 0xFFFFFFFFull : ~0ull;  // cols < 12000
        uint64_t avail = (~cur) & validm;
        uint64_t selbits = 0;
        // serial in-register select loop (pure ALU + shfl, no memory)
        while (avail && cnt < KPOST) {
            int b = __ffsll((unsigned long long)avail) - 1;
            if (lane == 0) sel[cnt] = iw * 64 + b;
            ++cnt;
            selbits |= (1ull << b);
            uint64_t km = (uint64_t)__shfl((unsigned long long)Dcur, b, 64);
            avail &= ~km;   // km has bit b set (self-IoU=1) -> progress guaranteed
        }
        // bulk OR of selected rows into p; only words >= iw can still be read
        bool l0 = (lane >= iw);
        bool l1 = (64 + lane >= iw);
        bool l2 = (128 + lane >= iw) && (lane < WORDS - 128);
        uint64_t sb = selbits;
        while (sb) {
            int ids[16];
            #pragma unroll
            for (int k = 0; k < 16; ++k) {
                ids[k] = sb ? (__ffsll((unsigned long long)sb) - 1) : -1;
                sb &= (sb - 1);
            }
            uint64_t v0[16], v1[16], v2[16];
            #pragma unroll
            for (int k = 0; k < 16; ++k) {
                v0[k] = 0; v1[k] = 0; v2[k] = 0;
                if (ids[k] >= 0) {
                    const uint64_t* row = mask + (size_t)(iw * 64 + ids[k]) * WORDS;
                    if (l0) v0[k] = row[lane];
                    if (l1) v1[k] = row[64 + lane];
                    if (l2) v2[k] = row[128 + lane];
                }
            }
            #pragma unroll
            for (int k = 0; k < 16; ++k) { p0 |= v0[k]; p1 |= v1[k]; p2 |= v2[k]; }
        }
        Dcur = Dnext;
    }
    if (lane == 0) state[6] = (uint32_t)cnt;
}

__global__ void k_gather(const float* __restrict__ bx0, const float* __restrict__ by0,
                         const float* __restrict__ bx1, const float* __restrict__ by1,
                         const int* __restrict__ sel, const uint32_t* __restrict__ state,
                         float4* __restrict__ out)
{
    int slot = blockIdx.x * blockDim.x + threadIdx.x;
    if (slot >= KPOST) return;
    uint32_t cnt = state[6];
    float4 v = make_float4(0.f, 0.f, 0.f, 0.f);
    if ((uint32_t)slot < cnt) {
        int i = sel[slot];
        v = make_float4(bx0[i], by0[i], bx1[i], by1[i]);
    }
    out[slot] = v;
}

extern "C" void kernel_launch(void* const* d_in, const int* in_sizes, int n_in,
                              void* d_out, int out_size, void* d_ws, size_t ws_size,
                              hipStream_t stream)
{
    const float* delta = (const float*)d_in[0];
    const float* score = (const float*)d_in[1];
    float4* out = (float4*)d_out;

    uint8_t* p = (uint8_t*)d_ws;
    auto alloc = [&](size_t bytes) -> void* {
        void* r = (void*)p;
        p += (bytes + 255) & ~(size_t)255;
        return r;
    };
    uint32_t* keys          = (uint32_t*)alloc((size_t)N_TOTAL * 4);
    uint32_t* hist1         = (uint32_t*)alloc(2048 * 4);
    uint32_t* hist2         = (uint32_t*)alloc(2048 * 4);
    uint32_t* hist3         = (uint32_t*)alloc(1024 * 4);
    uint32_t* state         = (uint32_t*)alloc(64);
    uint64_t* cand          = (uint64_t*)alloc((size_t)CAND_CAP * 8);
    uint32_t* sorted_anchor = (uint32_t*)alloc((size_t)NPAD * 4);
    float*    bx0           = (float*)alloc((size_t)NPAD * 4);
    float*    by0           = (float*)alloc((size_t)NPAD * 4);
    float*    bx1           = (float*)alloc((size_t)NPAD * 4);
    float*    by1           = (float*)alloc((size_t)NPAD * 4);
    float*    bar           = (float*)alloc((size_t)NPAD * 4);
    int*      sel           = (int*)alloc((size_t)KPOST * 4);
    uint64_t* mask          = (uint64_t*)alloc((size_t)NPAD * WORDS * 8);
    (void)ws_size; (void)n_in; (void)in_sizes; (void)out_size;

    const int B = 256;
    const int gN = (N_TOTAL + B - 1) / B;

    hipLaunchKernelGGL(k_init, dim3(68), dim3(B), 0, stream,
                       hist1, hist2, hist3, state, sorted_anchor);
    hipLaunchKernelGGL(k_keys, dim3(gN), dim3(B), 0, stream, delta, score, keys, hist1);
    hipLaunchKernelGGL(k_scan, dim3(1), dim3(B), 0, stream, hist1, state, 2048, 0);
    hipLaunchKernelGGL(k_hist2, dim3(gN), dim3(B), 0, stream, keys, state, hist2);
    hipLaunchKernelGGL(k_scan, dim3(1), dim3(B), 0, stream, hist2, state, 2048, 1);
    hipLaunchKernelGGL(k_hist3, dim3(gN), dim3(B), 0, stream, keys, state, hist3);
    hipLaunchKernelGGL(k_scan, dim3(1), dim3(B), 0, stream, hist3, state, 1024, 2);
    hipLaunchKernelGGL(k_compact, dim3(gN), dim3(B), 0, stream, keys, state, cand);
    hipLaunchKernelGGL(k_ranksort, dim3(CAND_CAP / B), dim3(B), 0, stream,
                       cand, state, sorted_anchor);
    hipLaunchKernelGGL(k_boxes, dim3(NPAD / B), dim3(B), 0, stream,
                       delta, sorted_anchor, bx0, by0, bx1, by1, bar);
    hipLaunchKernelGGL(k_mask, dim3(NPAD / 64), dim3(B), 0, stream,
                       bx0, by0, bx1, by1, bar, mask);
    hipLaunchKernelGGL(k_nms, dim3(1), dim3(64), 0, stream, mask, sel, state);
    hipLaunchKernelGGL(k_gather, dim3((KPOST + B - 1) / B), dim3(B), 0, stream,
                       bx0, by0, bx1, by1, sel, state, out);
}